// Round 12
// baseline (111.360 us; speedup 1.0000x reference)
//
#include <hip/hip_runtime.h>

#define B_SZ   2
#define NH     16
#define S_LEN  2048
#define DK     64
#define EMB    1024
#define M_TOT  (B_SZ * S_LEN)   // 4096
#define KT     64

typedef float          f32x4  __attribute__((ext_vector_type(4)));
typedef float          f32x16 __attribute__((ext_vector_type(16)));
typedef unsigned int   u32x4  __attribute__((ext_vector_type(4)));
typedef unsigned short u16x8  __attribute__((ext_vector_type(8)));
typedef unsigned short u16x4  __attribute__((ext_vector_type(4)));
typedef __bf16         bf16x8 __attribute__((ext_vector_type(8)));

static __device__ __forceinline__ f32x4 mfma16(u16x8 a, u16x8 b, f32x4 c) {
    return __builtin_amdgcn_mfma_f32_16x16x32_bf16(
        __builtin_bit_cast(bf16x8, a), __builtin_bit_cast(bf16x8, b), c, 0, 0, 0);
}
static __device__ __forceinline__ f32x16 mfma32(u16x8 a, u16x8 b, f32x16 c) {
    return __builtin_amdgcn_mfma_f32_32x32x16_bf16(
        __builtin_bit_cast(bf16x8, a), __builtin_bit_cast(bf16x8, b), c, 0, 0, 0);
}

// round-to-nearest-even fp32 -> bf16 (finite inputs)
static __device__ __forceinline__ unsigned short f2bf(float f) {
    unsigned int u = __builtin_bit_cast(unsigned int, f);
    u = (u + 0x7FFFu + ((u >> 16) & 1u)) >> 16;
    return (unsigned short)u;
}

// hardware 2^x
static __device__ __forceinline__ float exp2_hw(float x) {
    float r; asm("v_exp_f32 %0, %1" : "=v"(r) : "v"(x)); return r;
}

// raw barrier with compiler memory fence (no implicit vmcnt drain)
static __device__ __forceinline__ void barrier_raw() {
    asm volatile("s_barrier" ::: "memory");
}
#define VMCNT8() asm volatile("s_waitcnt vmcnt(8)" ::: "memory")
#define VMCNT4() asm volatile("s_waitcnt vmcnt(4)" ::: "memory")
#define VMCNT0() asm volatile("s_waitcnt vmcnt(0)" ::: "memory")

// async global -> LDS, 16B per lane; LDS dest = uniform base + lane*16
#define GLDS16(g, l)  __builtin_amdgcn_global_load_lds(                      \
    (const void __attribute__((address_space(1)))*)(g),                      \
    (void __attribute__((address_space(3)))*)(l), 16, 0, 0)

// ---------------------------------------------------------------- convert
__global__ __launch_bounds__(256) void cvt_kernel(
    const float* __restrict__ x,  const float* __restrict__ wq,
    const float* __restrict__ wk, const float* __restrict__ wv,
    unsigned short* __restrict__ xb,  unsigned short* __restrict__ wqb,
    unsigned short* __restrict__ wkb, unsigned short* __restrict__ wvb)
{
    long gid = (long)blockIdx.x * 256 + threadIdx.x;
    long e = gid * 4;
    const float* src; unsigned short* dst; long off;
    if      (e < 4194304L) { src = x;  dst = xb;  off = e; }
    else if (e < 5242880L) { src = wq; dst = wqb; off = e - 4194304L; }
    else if (e < 6291456L) { src = wk; dst = wkb; off = e - 5242880L; }
    else                   { src = wv; dst = wvb; off = e - 6291456L; }
    f32x4 v = *(const f32x4*)(src + off);
    u16x4 u;
    u[0] = f2bf(v[0]); u[1] = f2bf(v[1]); u[2] = f2bf(v[2]); u[3] = f2bf(v[3]);
    *(u16x4*)(dst + off) = u;
}

// ---------------------------------------------------------------- QKV GEMM
// Fused single GEMM: C[4096][3072] = xb[4096][1024] * Wfused[3072][1024]^T.
// 256x256 tile, BK=32, 4-deep LDS ring with counted vmcnt(8) (T3+T4).
__global__ __launch_bounds__(512) void qkv_gemm(
    const unsigned short* __restrict__ xb,
    const unsigned short* __restrict__ wb,   // fused [3072][1024] bf16
    const float* __restrict__ bq, const float* __restrict__ bk,
    const float* __restrict__ bv,
    unsigned short* __restrict__ qkv)
{
    const int tid  = threadIdx.x;
    const int lane = tid & 63;
    const int wid  = tid >> 6;
    const int wm   = wid >> 2, wn = wid & 3;    // 2 M-waves x 4 N-waves
    const int n0   = blockIdx.x * 256;
    const int m0   = blockIdx.y * 256;
    const int l15  = lane & 15;
    const int k4   = lane >> 4;

    __shared__ __align__(16) unsigned short Al[4][256 * 32];  // 64 KB
    __shared__ __align__(16) unsigned short Bl[4][256 * 32];  // 64 KB

    f32x4 acc[8][4];
#pragma unroll
    for (int i = 0; i < 8; ++i)
#pragma unroll
        for (int j = 0; j < 4; ++j)
            acc[i][j] = (f32x4){0.f, 0.f, 0.f, 0.f};

    const int row0 = tid >> 2, row1 = (512 + tid) >> 2;
    const int sl   = tid & 3;
    const int c0   = (sl ^ (row0 & 3)) << 3;
    const int c1   = (sl ^ (row1 & 3)) << 3;
    const int d0   = (wid * 64) * 8;
    const int d1   = (512 + wid * 64) * 8;
    const unsigned short* gA0 = xb + (size_t)(m0 + row0) * EMB + c0;
    const unsigned short* gA1 = xb + (size_t)(m0 + row1) * EMB + c1;
    const unsigned short* gB0 = wb + (size_t)(n0 + row0) * EMB + c0;
    const unsigned short* gB1 = wb + (size_t)(n0 + row1) * EMB + c1;

#define STAGE_A(kt, b) do {                                     \
        GLDS16(gA0 + (kt) * 32, &Al[b][d0]);                    \
        GLDS16(gA1 + (kt) * 32, &Al[b][d1]); } while (0)
#define STAGE_B(kt, b) do {                                     \
        GLDS16(gB0 + (kt) * 32, &Bl[b][d0]);                    \
        GLDS16(gB1 + (kt) * 32, &Bl[b][d1]); } while (0)

    const int rsl = (k4 ^ (l15 & 3)) << 3;
    const int abase = wm * 128 + l15;
    const int bbase = wn * 64 + l15;

    STAGE_A(0, 0); STAGE_B(0, 0);
    STAGE_A(1, 1); STAGE_B(1, 1);
    STAGE_A(2, 2); STAGE_B(2, 2);
    VMCNT8();
    barrier_raw();

    for (int kt = 0; kt < 32; ++kt) {
        const int b = kt & 3;
        const unsigned short* Ab = Al[b];
        const unsigned short* Bb = Bl[b];

        u16x8 bfr[4], afr[4];
#pragma unroll
        for (int j = 0; j < 4; ++j)
            bfr[j] = *(const u16x8*)&Bb[(bbase + j * 16) * 32 + rsl];
#pragma unroll
        for (int i = 0; i < 4; ++i)
            afr[i] = *(const u16x8*)&Ab[(abase + i * 16) * 32 + rsl];
        if (kt + 3 < 32) STAGE_A(kt + 3, (kt + 3) & 3);
        __builtin_amdgcn_s_setprio(1);
#pragma unroll
        for (int i = 0; i < 4; ++i)
#pragma unroll
            for (int j = 0; j < 4; ++j)
                acc[i][j] = mfma16(afr[i], bfr[j], acc[i][j]);
        __builtin_amdgcn_s_setprio(0);
        barrier_raw();

#pragma unroll
        for (int i = 0; i < 4; ++i)
            afr[i] = *(const u16x8*)&Ab[(abase + (4 + i) * 16) * 32 + rsl];
        if (kt + 3 < 32) STAGE_B(kt + 3, (kt + 3) & 3);
        __builtin_amdgcn_s_setprio(1);
#pragma unroll
        for (int i = 0; i < 4; ++i)
#pragma unroll
            for (int j = 0; j < 4; ++j)
                acc[4 + i][j] = mfma16(afr[i], bfr[j], acc[4 + i][j]);
        __builtin_amdgcn_s_setprio(0);

        if (kt == 29)      VMCNT4();
        else if (kt == 30) VMCNT0();
        else               VMCNT8();
        barrier_raw();
    }

    const int mat = n0 >> 10;
    const float* bias = (mat == 0) ? bq : ((mat == 1) ? bk : bv);
    unsigned short* dst = qkv + (size_t)mat * ((size_t)M_TOT * EMB);
    const int nb = (n0 & 1023) + wn * 64;
#pragma unroll
    for (int fc = 0; fc < 4; ++fc) {
        const int nl = nb + fc * 16 + l15;
        const float bvv = bias[nl];
        const int h = nl >> 6, d = nl & 63;
#pragma unroll
        for (int fr = 0; fr < 8; ++fr) {
#pragma unroll
            for (int rr = 0; rr < 4; ++rr) {
                const int m = m0 + wm * 128 + fr * 16 + k4 * 4 + rr;
                const int bb = m >> 11, s = m & 2047;
                dst[((size_t)((bb * NH + h) * S_LEN + s)) * DK + d] =
                    f2bf(acc[fr][fc][rr] + bvv);
            }
        }
    }
#undef STAGE_A
#undef STAGE_B
}

// ---------------------------------------------------------------- attention
// 8 waves (512 thr) = 4 K-interleave groups x 2 q-waves, QT=64.  splitK=4
// shortens the longest serial chain to 8 iters; grid 32x32 = 1024 blocks
// (4/CU: 2 resident + 2 queued -> refill).  Single-buffer LDS + reg
// prefetch (2 barriers/iter).  Swapped QK^T (32x32 MFMA), exp2 softmax,
// defer-max, VALU row-sum, cvt_pk+permlane32 P->B, 4-way LSE merge.
__global__ __launch_bounds__(512) void attn_kernel(
    const unsigned short* __restrict__ Q,
    const unsigned short* __restrict__ K,
    const unsigned short* __restrict__ V,
    const int* __restrict__ mskp,
    float* __restrict__ out)
{
    const int tid = threadIdx.x, lane = tid & 63, wid = tid >> 6;
    const int grp = wid >> 1, qw = wid & 1;
    const int l31 = lane & 31, H = lane >> 5;
    const int bh = blockIdx.x;
    const int h  = bh & 15, b = bh >> 4;
    const int qt = blockIdx.y;             // 0..31 (64-row q-tile)
    const int q0 = qt * 64;
    const size_t hoff = ((size_t)(b * NH + h)) * S_LEN * DK;
    const unsigned short* Qh = Q + hoff;
    const unsigned short* Kh = K + hoff;
    const unsigned short* Vh = V + hoff;
    const int msk = *mskp;
    const int ntiles = msk ? (qt + 1) : (S_LEN / KT);
    const int niter  = (ntiles + 3) >> 2;

    __shared__ __align__(16) unsigned short Kl[4][64 * 64];   // 32 KB
    __shared__ __align__(16) unsigned short Vt[4][64 * 64];   // 32 KB
    __shared__ float MLbuf[768];
    unsigned short* Kg = Kl[grp];
    unsigned short* Vg = Vt[grp];

    const int qrow = q0 + qw * 32 + l31;
    const int qmin = q0 + qw * 32;
    u16x8 qf[4];
#pragma unroll
    for (int ks = 0; ks < 4; ++ks)
        qf[ks] = *(const u16x8*)(Qh + (size_t)qrow * DK + ks * 16 + H * 8);

    f32x16 o0, o1;
#pragma unroll
    for (int i = 0; i < 16; ++i) { o0[i] = 0.f; o1[i] = 0.f; }
    float mx = -1e30f, lsum = 0.f;

    // staging: 128 threads/group, 4 rows each (rows j*16 + (gt>>3))
    const int gt  = tid & 127;
    const int sc8 = gt & 7;
    const int rb  = gt >> 3;                 // 0..15
    int kwo[4], vwo[4];
#pragma unroll
    for (int j = 0; j < 4; ++j) {
        const int rj = j * 16 + rb;
        kwo[j] = rj * 64 + ((sc8 ^ (rb & 7)) << 3);
        vwo[j] = (((rj >> 3) ^ sc8) << 3) + (rj & 7);
    }

    const int dsw0 = l31 >> 3, dsw1 = 4 + (l31 >> 3);
    const int rsw  = l31 & 7;
    const float SC2 = 0.125f * 1.4426950408889634f;   // fold log2(e)
    const int idx  = qw * 64 + lane;                  // merge row (0..127)

    // prologue: load tile 'grp' into regs (rows <=255, always in-bounds)
    u16x8 kr[4], vr[4];
#pragma unroll
    for (int j = 0; j < 4; ++j) {
        const size_t ro = ((size_t)grp * KT + j * 16 + rb) * DK + sc8 * 8;
        kr[j] = *(const u16x8*)(Kh + ro);
        vr[j] = *(const u16x8*)(Vh + ro);
    }

    for (int it = 0; it < niter; ++it) {
        const int kt = 4 * it + grp;
        const bool act = kt < ntiles;
        __syncthreads();   // previous LDS contents fully consumed
        if (act) {
#pragma unroll
            for (int j = 0; j < 4; ++j) {
                *(u16x8*)&Kg[kwo[j]] = kr[j];
#pragma unroll
                for (int e = 0; e < 8; ++e)
                    Vg[(sc8 * 8 + e) * 64 + vwo[j]] = vr[j][e];
            }
        }
        __syncthreads();   // staged tiles visible

        if (kt + 4 < ntiles) {   // prefetch next tile; hides under compute
#pragma unroll
            for (int j = 0; j < 4; ++j) {
                const size_t ro = ((size_t)(kt + 4) * KT + j * 16 + rb) * DK + sc8 * 8;
                kr[j] = *(const u16x8*)(Kh + ro);
                vr[j] = *(const u16x8*)(Vh + ro);
            }
        }

        if (!act || (msk && kt * KT > qmin + 31)) continue;  // no barriers below

        // ---- S^T = K Q^T ----
        f32x16 st0, st1;
#pragma unroll
        for (int i = 0; i < 16; ++i) { st0[i] = 0.f; st1[i] = 0.f; }
        __builtin_amdgcn_s_setprio(1);
#pragma unroll
        for (int ks = 0; ks < 4; ++ks) {
            const int g = (((ks << 1) + H) ^ rsw) << 3;
            u16x8 kf0 = *(const u16x8*)&Kg[l31 * 64 + g];
            u16x8 kf1 = *(const u16x8*)&Kg[(32 + l31) * 64 + g];
            st0 = mfma32(kf0, qf[ks], st0);
            st1 = mfma32(kf1, qf[ks], st1);
        }
        __builtin_amdgcn_s_setprio(0);

        // ---- scale (exp2 domain) + causal mask ----
        st0 *= SC2;
        st1 *= SC2;
        float p[32];
#pragma unroll
        for (int r = 0; r < 16; ++r) { p[r] = st0[r]; p[16 + r] = st1[r]; }
        const bool needmask = msk && (kt * KT + 63 > qrow);
        if (needmask) {
#pragma unroll
            for (int r = 0; r < 16; ++r) {
                const int krow = (r & 3) + 8 * (r >> 2) + 4 * H;
                if (kt * KT + krow > qrow)      p[r]      = -1e30f;
                if (kt * KT + 32 + krow > qrow) p[16 + r] = -1e30f;
            }
        }

        // ---- tile max: register tree + one shfl(32); defer-max rescale ----
        float t8[8];
#pragma unroll
        for (int i = 0; i < 8; ++i)
            t8[i] = fmaxf(fmaxf(p[i], p[i + 8]), fmaxf(p[i + 16], p[i + 24]));
#pragma unroll
        for (int i = 0; i < 4; ++i) t8[i] = fmaxf(t8[i], t8[i + 4]);
        float mt = fmaxf(fmaxf(t8[0], t8[1]), fmaxf(t8[2], t8[3]));
        mt = fmaxf(mt, __shfl_xor(mt, 32, 64));

        if (!__all(mt <= mx + 11.54f)) {   // 8 nats in log2 domain
            const float mn = fmaxf(mx, mt);
            const float al = exp2_hw(mx - mn);
            mx = mn;
            lsum *= al;
            o0 *= al; o1 *= al;
        }

        float s8[8];
#pragma unroll
        for (int i = 0; i < 8; ++i) s8[i] = 0.f;
#pragma unroll
        for (int r = 0; r < 32; ++r) {
            p[r] = exp2_hw(p[r] - mx);
            s8[r & 7] += p[r];
        }
        float ls = ((s8[0] + s8[1]) + (s8[2] + s8[3])) +
                   ((s8[4] + s8[5]) + (s8[6] + s8[7]));
        ls += __shfl_xor(ls, 32, 64);
        lsum += ls;

        // ---- P^T -> bf16 B-fragments, then PV ----
        __builtin_amdgcn_s_setprio(1);
#pragma unroll
        for (int ks = 0; ks < 4; ++ks) {
            const int bb = ks * 8;
            unsigned int wa, wb2, wc, wd;
            asm("v_cvt_pk_bf16_f32 %0, %1, %2" : "=v"(wa)  : "v"(p[bb + 0]), "v"(p[bb + 1]));
            asm("v_cvt_pk_bf16_f32 %0, %1, %2" : "=v"(wb2) : "v"(p[bb + 2]), "v"(p[bb + 3]));
            asm("v_cvt_pk_bf16_f32 %0, %1, %2" : "=v"(wc)  : "v"(p[bb + 4]), "v"(p[bb + 5]));
            asm("v_cvt_pk_bf16_f32 %0, %1, %2" : "=v"(wd)  : "v"(p[bb + 6]), "v"(p[bb + 7]));
            asm volatile("v_permlane32_swap_b32 %0, %1" : "+v"(wa),  "+v"(wc));
            asm volatile("v_permlane32_swap_b32 %0, %1" : "+v"(wb2), "+v"(wd));
            u32x4 wv; wv[0] = wa; wv[1] = wb2; wv[2] = wc; wv[3] = wd;
            const u16x8 pb = __builtin_bit_cast(u16x8, wv);
            const int kg = (ks << 1) + H;
            u16x8 vf0 = *(const u16x8*)&Vg[l31 * 64        + ((kg ^ dsw0) << 3)];
            u16x8 vf1 = *(const u16x8*)&Vg[(32 + l31) * 64 + ((kg ^ dsw1) << 3)];
            o0 = mfma32(vf0, pb, o0);
            o1 = mfma32(vf1, pb, o1);
        }
        __builtin_amdgcn_s_setprio(0);
    }

    // ---- 4-way LSE merge: (0<-1), (2<-3), then (0<-2) ----
    // MO regions: 128 rows x 32 floats = 16 KB each; grp1 -> Kl[0..16K),
    // grp3 -> Vt[0..16K); step C: grp2 -> Kl.  m/l pairs in MLbuf.
    __syncthreads();   // all compute + LDS reads done
    if (grp == 1 || grp == 3) {
        float* MO = ((grp == 1) ? (float*)Kl : (float*)Vt) + idx * 32;
#pragma unroll
        for (int i = 0; i < 16; ++i) {
            MO[(i + idx) & 31]      = o0[i];
            MO[(16 + i + idx) & 31] = o1[i];
        }
        float* ML = MLbuf + (grp == 1 ? 0 : 256);
        ML[idx * 2]     = mx;
        ML[idx * 2 + 1] = lsum;
    }
    __syncthreads();
    if (grp == 0 || grp == 2) {
        const float* MO = ((grp == 0) ? (float*)Kl : (float*)Vt) + idx * 32;
        const float* ML = MLbuf + (grp == 0 ? 0 : 256);
        const float m2 = ML[idx * 2], l2 = ML[idx * 2 + 1];
        const float mn = fmaxf(mx, m2);
        const float ea = exp2_hw(mx - mn);
        const float eb = exp2_hw(m2 - mn);
        mx = mn;
        lsum = lsum * ea + l2 * eb;
#pragma unroll
        for (int i = 0; i < 16; ++i) {
            o0[i] = o0[i] * ea + MO[(i + idx) & 31] * eb;
            o1[i] = o1[i] * ea + MO[(16 + i + idx) & 31] * eb;
        }
    }
    __syncthreads();   // round-A reads done before grp2 overwrites Kl
    if (grp == 2) {
        float* MO = (float*)Kl + idx * 32;
#pragma unroll
        for (int i = 0; i < 16; ++i) {
            MO[(i + idx) & 31]      = o0[i];
            MO[(16 + i + idx) & 31] = o1[i];
        }
        MLbuf[512 + idx * 2]     = mx;
        MLbuf[512 + idx * 2 + 1] = lsum;
    }
    __syncthreads();
    if (grp == 0) {
        const float* MO = (float*)Kl + idx * 32;
        const float m2 = MLbuf[512 + idx * 2], l2 = MLbuf[512 + idx * 2 + 1];
        const float mn = fmaxf(mx, m2);
        const float ea = exp2_hw(mx - mn);
        const float eb = exp2_hw(m2 - mn);
        const float inv = 1.f / (lsum * ea + l2 * eb);
        float* orow = out + ((size_t)(b * S_LEN) + qrow) * EMB + h * DK;
#pragma unroll
        for (int g = 0; g < 4; ++g) {
            f32x4 w0, w1;
#pragma unroll
            for (int i = 0; i < 4; ++i) {
                w0[i] = (o0[4 * g + i] * ea + MO[(4 * g + i + idx) & 31] * eb) * inv;
                w1[i] = (o1[4 * g + i] * ea + MO[(16 + 4 * g + i + idx) & 31] * eb) * inv;
            }
            *(f32x4*)&orow[8 * g + 4 * H]      = w0;
            *(f32x4*)&orow[32 + 8 * g + 4 * H] = w1;
        }
    }
}

// ---------------------------------------------------------------- launch
extern "C" void kernel_launch(void* const* d_in, const int* in_sizes, int n_in,
                              void* d_out, int out_size, void* d_ws, size_t ws_size,
                              hipStream_t stream)
{
    const float* x  = (const float*)d_in[0];
    const float* wq = (const float*)d_in[1];
    const float* bq = (const float*)d_in[2];
    const float* wk = (const float*)d_in[3];
    const float* bk = (const float*)d_in[4];
    const float* wv = (const float*)d_in[5];
    const float* bv = (const float*)d_in[6];
    const int* msk  = (const int*)d_in[7];
    float* out = (float*)d_out;

    unsigned short* xb  = (unsigned short*)d_ws;
    unsigned short* wb  = xb + (size_t)M_TOT * EMB;   // fused [3072][1024]
    unsigned short* qkv = wb + (size_t)3 * 1024 * 1024;

    cvt_kernel<<<7168, 256, 0, stream>>>(x, wq, wk, wv,
                                         xb, wb, wb + 1024 * 1024, wb + 2 * 1024 * 1024);
    qkv_gemm<<<dim3(12, 16, 1), 512, 0, stream>>>(xb, wb, bq, bk, bv, qkv);
    attn_kernel<<<dim3(32, 32, 1), 512, 0, stream>>>(
        qkv, qkv + (size_t)M_TOT * EMB, qkv + (size_t)2 * M_TOT * EMB, msk, out);
}

// Round 13
// 87.972 us; speedup vs baseline: 1.2659x; 1.2659x over previous
//
#include <hip/hip_runtime.h>

#define B_SZ   2
#define NH     16
#define S_LEN  2048
#define DK     64
#define EMB    1024
#define M_TOT  (B_SZ * S_LEN)   // 4096
#define KT     64

typedef float          f32x4  __attribute__((ext_vector_type(4)));
typedef float          f32x16 __attribute__((ext_vector_type(16)));
typedef unsigned int   u32x4  __attribute__((ext_vector_type(4)));
typedef unsigned short u16x8  __attribute__((ext_vector_type(8)));
typedef unsigned short u16x4  __attribute__((ext_vector_type(4)));
typedef __bf16         bf16x8 __attribute__((ext_vector_type(8)));

static __device__ __forceinline__ f32x4 mfma16(u16x8 a, u16x8 b, f32x4 c) {
    return __builtin_amdgcn_mfma_f32_16x16x32_bf16(
        __builtin_bit_cast(bf16x8, a), __builtin_bit_cast(bf16x8, b), c, 0, 0, 0);
}
static __device__ __forceinline__ f32x16 mfma32(u16x8 a, u16x8 b, f32x16 c) {
    return __builtin_amdgcn_mfma_f32_32x32x16_bf16(
        __builtin_bit_cast(bf16x8, a), __builtin_bit_cast(bf16x8, b), c, 0, 0, 0);
}

// round-to-nearest-even fp32 -> bf16 (finite inputs)
static __device__ __forceinline__ unsigned short f2bf(float f) {
    unsigned int u = __builtin_bit_cast(unsigned int, f);
    u = (u + 0x7FFFu + ((u >> 16) & 1u)) >> 16;
    return (unsigned short)u;
}

// hardware 2^x
static __device__ __forceinline__ float exp2_hw(float x) {
    float r; asm("v_exp_f32 %0, %1" : "=v"(r) : "v"(x)); return r;
}

// raw barrier with compiler memory fence (no implicit vmcnt drain)
static __device__ __forceinline__ void barrier_raw() {
    asm volatile("s_barrier" ::: "memory");
}
#define VMCNT8() asm volatile("s_waitcnt vmcnt(8)" ::: "memory")
#define VMCNT4() asm volatile("s_waitcnt vmcnt(4)" ::: "memory")
#define VMCNT0() asm volatile("s_waitcnt vmcnt(0)" ::: "memory")

// async global -> LDS, 16B per lane; LDS dest = uniform base + lane*16
#define GLDS16(g, l)  __builtin_amdgcn_global_load_lds(                      \
    (const void __attribute__((address_space(1)))*)(g),                      \
    (void __attribute__((address_space(3)))*)(l), 16, 0, 0)

// ---------------------------------------------------------------- convert
__global__ __launch_bounds__(256) void cvt_kernel(
    const float* __restrict__ x,  const float* __restrict__ wq,
    const float* __restrict__ wk, const float* __restrict__ wv,
    unsigned short* __restrict__ xb,  unsigned short* __restrict__ wqb,
    unsigned short* __restrict__ wkb, unsigned short* __restrict__ wvb)
{
    long gid = (long)blockIdx.x * 256 + threadIdx.x;
    long e = gid * 4;
    const float* src; unsigned short* dst; long off;
    if      (e < 4194304L) { src = x;  dst = xb;  off = e; }
    else if (e < 5242880L) { src = wq; dst = wqb; off = e - 4194304L; }
    else if (e < 6291456L) { src = wk; dst = wkb; off = e - 5242880L; }
    else                   { src = wv; dst = wvb; off = e - 6291456L; }
    f32x4 v = *(const f32x4*)(src + off);
    u16x4 u;
    u[0] = f2bf(v[0]); u[1] = f2bf(v[1]); u[2] = f2bf(v[2]); u[3] = f2bf(v[3]);
    *(u16x4*)(dst + off) = u;
}

// ---------------------------------------------------------------- QKV GEMM
// Fused single GEMM: C[4096][3072] = xb[4096][1024] * Wfused[3072][1024]^T.
// 256x256 tile, BK=32, 4-deep LDS ring with counted vmcnt(8) (T3+T4).
// XCD-aware bijective block swizzle (T1): each XCD gets 24 consecutive ids
// in y-inner order -> B-panels reused 16x from the XCD-private L2.
__global__ __launch_bounds__(512) void qkv_gemm(
    const unsigned short* __restrict__ xb,
    const unsigned short* __restrict__ wb,   // fused [3072][1024] bf16
    const float* __restrict__ bq, const float* __restrict__ bk,
    const float* __restrict__ bv,
    unsigned short* __restrict__ qkv)
{
    const int tid  = threadIdx.x;
    const int lane = tid & 63;
    const int wid  = tid >> 6;
    const int wm   = wid >> 2, wn = wid & 3;    // 2 M-waves x 4 N-waves
    // ---- XCD swizzle: lid -> nid = (lid%8)*24 + lid/8 (bijective, 192) ----
    const int lid  = blockIdx.y * 12 + blockIdx.x;
    const int nid  = (lid & 7) * 24 + (lid >> 3);
    const int n0   = (nid >> 4) * 256;          // x' = nid/16 (0..11)
    const int m0   = (nid & 15) * 256;          // y' = nid%16
    const int l15  = lane & 15;
    const int k4   = lane >> 4;

    __shared__ __align__(16) unsigned short Al[4][256 * 32];  // 64 KB
    __shared__ __align__(16) unsigned short Bl[4][256 * 32];  // 64 KB

    f32x4 acc[8][4];
#pragma unroll
    for (int i = 0; i < 8; ++i)
#pragma unroll
        for (int j = 0; j < 4; ++j)
            acc[i][j] = (f32x4){0.f, 0.f, 0.f, 0.f};

    const int row0 = tid >> 2, row1 = (512 + tid) >> 2;
    const int sl   = tid & 3;
    const int c0   = (sl ^ (row0 & 3)) << 3;
    const int c1   = (sl ^ (row1 & 3)) << 3;
    const int d0   = (wid * 64) * 8;
    const int d1   = (512 + wid * 64) * 8;
    const unsigned short* gA0 = xb + (size_t)(m0 + row0) * EMB + c0;
    const unsigned short* gA1 = xb + (size_t)(m0 + row1) * EMB + c1;
    const unsigned short* gB0 = wb + (size_t)(n0 + row0) * EMB + c0;
    const unsigned short* gB1 = wb + (size_t)(n0 + row1) * EMB + c1;

#define STAGE_A(kt, b) do {                                     \
        GLDS16(gA0 + (kt) * 32, &Al[b][d0]);                    \
        GLDS16(gA1 + (kt) * 32, &Al[b][d1]); } while (0)
#define STAGE_B(kt, b) do {                                     \
        GLDS16(gB0 + (kt) * 32, &Bl[b][d0]);                    \
        GLDS16(gB1 + (kt) * 32, &Bl[b][d1]); } while (0)

    const int rsl = (k4 ^ (l15 & 3)) << 3;
    const int abase = wm * 128 + l15;
    const int bbase = wn * 64 + l15;

    STAGE_A(0, 0); STAGE_B(0, 0);
    STAGE_A(1, 1); STAGE_B(1, 1);
    STAGE_A(2, 2); STAGE_B(2, 2);
    VMCNT8();
    barrier_raw();

    for (int kt = 0; kt < 32; ++kt) {
        const int b = kt & 3;
        const unsigned short* Ab = Al[b];
        const unsigned short* Bb = Bl[b];

        u16x8 bfr[4], afr[4];
#pragma unroll
        for (int j = 0; j < 4; ++j)
            bfr[j] = *(const u16x8*)&Bb[(bbase + j * 16) * 32 + rsl];
#pragma unroll
        for (int i = 0; i < 4; ++i)
            afr[i] = *(const u16x8*)&Ab[(abase + i * 16) * 32 + rsl];
        if (kt + 3 < 32) STAGE_A(kt + 3, (kt + 3) & 3);
        __builtin_amdgcn_s_setprio(1);
#pragma unroll
        for (int i = 0; i < 4; ++i)
#pragma unroll
            for (int j = 0; j < 4; ++j)
                acc[i][j] = mfma16(afr[i], bfr[j], acc[i][j]);
        __builtin_amdgcn_s_setprio(0);
        barrier_raw();

#pragma unroll
        for (int i = 0; i < 4; ++i)
            afr[i] = *(const u16x8*)&Ab[(abase + (4 + i) * 16) * 32 + rsl];
        if (kt + 3 < 32) STAGE_B(kt + 3, (kt + 3) & 3);
        __builtin_amdgcn_s_setprio(1);
#pragma unroll
        for (int i = 0; i < 4; ++i)
#pragma unroll
            for (int j = 0; j < 4; ++j)
                acc[4 + i][j] = mfma16(afr[i], bfr[j], acc[4 + i][j]);
        __builtin_amdgcn_s_setprio(0);

        if (kt == 29)      VMCNT4();
        else if (kt == 30) VMCNT0();
        else               VMCNT8();
        barrier_raw();
    }

    const int mat = n0 >> 10;
    const float* bias = (mat == 0) ? bq : ((mat == 1) ? bk : bv);
    unsigned short* dst = qkv + (size_t)mat * ((size_t)M_TOT * EMB);
    const int nb = (n0 & 1023) + wn * 64;
#pragma unroll
    for (int fc = 0; fc < 4; ++fc) {
        const int nl = nb + fc * 16 + l15;
        const float bvv = bias[nl];
        const int h = nl >> 6, d = nl & 63;
#pragma unroll
        for (int fr = 0; fr < 8; ++fr) {
#pragma unroll
            for (int rr = 0; rr < 4; ++rr) {
                const int m = m0 + wm * 128 + fr * 16 + k4 * 4 + rr;
                const int bb = m >> 11, s = m & 2047;
                dst[((size_t)((bb * NH + h) * S_LEN + s)) * DK + d] =
                    f2bf(acc[fr][fc][rr] + bvv);
            }
        }
    }
#undef STAGE_A
#undef STAGE_B
}

// ---------------------------------------------------------------- attention
// (round-8 proven kernel, byte-identical: 8 waves = 4 q-waves x 2 K-parity
// groups, single-barrier double-buffered pipeline, swapped QK^T, exp2
// softmax, defer-max, lsum via ones-MFMA, cvt_pk+permlane32 P->B.)
__global__ __launch_bounds__(512) void attn_kernel(
    const unsigned short* __restrict__ Q,
    const unsigned short* __restrict__ K,
    const unsigned short* __restrict__ V,
    const int* __restrict__ mskp,
    float* __restrict__ out)
{
    const int tid = threadIdx.x, lane = tid & 63, wid = tid >> 6;
    const int grp = wid >> 2, qw = wid & 3;
    const int l31 = lane & 31, H = lane >> 5;
    const int bh = blockIdx.x;
    const int h  = bh & 15, b = bh >> 4;
    const int y  = blockIdx.y;
    const int qt = (y < 8) ? y : 23 - y;   // pairs (y,y+8): qt sums to 15
    const int q0 = qt * 128;
    const size_t hoff = ((size_t)(b * NH + h)) * S_LEN * DK;
    const unsigned short* Qh = Q + hoff;
    const unsigned short* Kh = K + hoff;
    const unsigned short* Vh = V + hoff;
    const int msk = *mskp;
    const int ntiles = msk ? (2 * qt + 2) : (S_LEN / KT);  // always even
    const int niter  = ntiles >> 1;

    __shared__ __align__(16) unsigned short Kl[2][2][64 * 64];  // [grp][buf]
    __shared__ __align__(16) unsigned short Vt[2][2][64 * 64];
    __shared__ float MLbuf[512];

    const int qrow = q0 + qw * 32 + l31;
    u16x8 qf[4];
#pragma unroll
    for (int ks = 0; ks < 4; ++ks)
        qf[ks] = *(const u16x8*)(Qh + (size_t)qrow * DK + ks * 16 + H * 8);

    u16x8 ones1;
#pragma unroll
    for (int i = 0; i < 8; ++i) ones1[i] = 0x3F80;   // bf16 1.0

    f32x16 o0, o1, lacc;
#pragma unroll
    for (int i = 0; i < 16; ++i) { o0[i] = 0.f; o1[i] = 0.f; lacc[i] = 0.f; }
    float mx = -1e30f;

    const int gt  = tid & 255;              // thread within group
    const int sr0 = gt >> 3, sc8 = gt & 7, sr1 = sr0 + 32;
    const int kwo0 = sr0 * 64 + ((sc8 ^ (sr0 & 7)) << 3);
    const int kwo1 = sr1 * 64 + ((sc8 ^ (sr1 & 7)) << 3);
    const int vwo0 = (((sr0 >> 3) ^ sc8) << 3) + (sr0 & 7);
    const int vwo1 = (((sr1 >> 3) ^ sc8) << 3) + (sr1 & 7);

    const int qmin = q0 + qw * 32;
    const int dsw0 = l31 >> 3, dsw1 = 4 + (l31 >> 3);
    const int rsw  = l31 & 7;
    const float SC2 = 0.125f * 1.4426950408889634f;   // fold log2(e)

    // ---- prologue: stage tile 'grp' into buf0, prefetch tile grp+2 ----
    u16x8 kr[2], vr[2];
    {
        const unsigned short* K0 = Kh + (size_t)grp * KT * DK;
        const unsigned short* V0 = Vh + (size_t)grp * KT * DK;
        kr[0] = *(const u16x8*)(K0 + (size_t)sr0 * DK + sc8 * 8);
        vr[0] = *(const u16x8*)(V0 + (size_t)sr0 * DK + sc8 * 8);
        kr[1] = *(const u16x8*)(K0 + (size_t)sr1 * DK + sc8 * 8);
        vr[1] = *(const u16x8*)(V0 + (size_t)sr1 * DK + sc8 * 8);
        unsigned short* Kg = Kl[grp][0];
        unsigned short* Vg = Vt[grp][0];
        *(u16x8*)&Kg[kwo0] = kr[0];
        *(u16x8*)&Kg[kwo1] = kr[1];
#pragma unroll
        for (int e = 0; e < 8; ++e) {
            Vg[(sc8 * 8 + e) * 64 + vwo0] = vr[0][e];
            Vg[(sc8 * 8 + e) * 64 + vwo1] = vr[1][e];
        }
        if (grp + 2 < ntiles) {
            const unsigned short* Kn = Kh + (size_t)(grp + 2) * KT * DK;
            const unsigned short* Vn = Vh + (size_t)(grp + 2) * KT * DK;
            kr[0] = *(const u16x8*)(Kn + (size_t)sr0 * DK + sc8 * 8);
            vr[0] = *(const u16x8*)(Vn + (size_t)sr0 * DK + sc8 * 8);
            kr[1] = *(const u16x8*)(Kn + (size_t)sr1 * DK + sc8 * 8);
            vr[1] = *(const u16x8*)(Vn + (size_t)sr1 * DK + sc8 * 8);
        }
    }
    __syncthreads();

    int cur = 0;
    for (int it = 0; it < niter; ++it) {
        const int kt = 2 * it + grp;   // kt <= ntiles-1 always

        // ---- write NEXT tile (kt+2) into buf^1; overlaps with compute ----
        if (kt + 2 < ntiles) {
            unsigned short* Kg = Kl[grp][cur ^ 1];
            unsigned short* Vg = Vt[grp][cur ^ 1];
            *(u16x8*)&Kg[kwo0] = kr[0];
            *(u16x8*)&Kg[kwo1] = kr[1];
#pragma unroll
            for (int e = 0; e < 8; ++e) {
                Vg[(sc8 * 8 + e) * 64 + vwo0] = vr[0][e];
                Vg[(sc8 * 8 + e) * 64 + vwo1] = vr[1][e];
            }
        }
        // ---- prefetch tile kt+4 into regs ----
        if (kt + 4 < ntiles) {
            const unsigned short* Kn = Kh + (size_t)(kt + 4) * KT * DK;
            const unsigned short* Vn = Vh + (size_t)(kt + 4) * KT * DK;
            kr[0] = *(const u16x8*)(Kn + (size_t)sr0 * DK + sc8 * 8);
            vr[0] = *(const u16x8*)(Vn + (size_t)sr0 * DK + sc8 * 8);
            kr[1] = *(const u16x8*)(Kn + (size_t)sr1 * DK + sc8 * 8);
            vr[1] = *(const u16x8*)(Vn + (size_t)sr1 * DK + sc8 * 8);
        }

        // ---- compute tile kt from buf[cur] (skip if fully masked) ----
        if (!(msk && kt * KT > qmin + 31)) {
            const unsigned short* Kg = Kl[grp][cur];
            const unsigned short* Vg = Vt[grp][cur];

            // S^T = K Q^T
            f32x16 st0, st1;
#pragma unroll
            for (int i = 0; i < 16; ++i) { st0[i] = 0.f; st1[i] = 0.f; }
            __builtin_amdgcn_s_setprio(1);
#pragma unroll
            for (int ks = 0; ks < 4; ++ks) {
                const int g = (((ks << 1) + H) ^ rsw) << 3;
                u16x8 kf0 = *(const u16x8*)&Kg[l31 * 64 + g];
                u16x8 kf1 = *(const u16x8*)&Kg[(32 + l31) * 64 + g];
                st0 = mfma32(kf0, qf[ks], st0);
                st1 = mfma32(kf1, qf[ks], st1);
            }
            __builtin_amdgcn_s_setprio(0);

            // scale (exp2 domain, packed) + causal mask
            st0 *= SC2;
            st1 *= SC2;
            float p[32];
#pragma unroll
            for (int r = 0; r < 16; ++r) { p[r] = st0[r]; p[16 + r] = st1[r]; }
            const bool needmask = msk && (kt * KT + 63 > qrow);
            if (needmask) {
#pragma unroll
                for (int r = 0; r < 16; ++r) {
                    const int krow = (r & 3) + 8 * (r >> 2) + 4 * H;
                    if (kt * KT + krow > qrow)      p[r]      = -1e30f;
                    if (kt * KT + 32 + krow > qrow) p[16 + r] = -1e30f;
                }
            }

            // tile max: register tree + one shfl(32); defer-max rescale
            float t8[8];
#pragma unroll
            for (int i = 0; i < 8; ++i)
                t8[i] = fmaxf(fmaxf(p[i], p[i + 8]), fmaxf(p[i + 16], p[i + 24]));
#pragma unroll
            for (int i = 0; i < 4; ++i) t8[i] = fmaxf(t8[i], t8[i + 4]);
            float mt = fmaxf(fmaxf(t8[0], t8[1]), fmaxf(t8[2], t8[3]));
            mt = fmaxf(mt, __shfl_xor(mt, 32, 64));

            if (!__all(mt <= mx + 11.54f)) {   // 8 nats in log2 domain
                const float mn = fmaxf(mx, mt);
                const float al = exp2_hw(mx - mn);
                mx = mn;
                o0 *= al; o1 *= al;
                lacc[0] *= al;                  // only reg 0 of lacc is used
            }

#pragma unroll
            for (int r = 0; r < 32; ++r) p[r] = exp2_hw(p[r] - mx);

            // P^T -> bf16 B-fragments; PV + row-sum via ones-MFMA
            __builtin_amdgcn_s_setprio(1);
#pragma unroll
            for (int ks = 0; ks < 4; ++ks) {
                const int bb = ks * 8;
                unsigned int wa, wb2, wc, wd;
                asm("v_cvt_pk_bf16_f32 %0, %1, %2" : "=v"(wa)  : "v"(p[bb + 0]), "v"(p[bb + 1]));
                asm("v_cvt_pk_bf16_f32 %0, %1, %2" : "=v"(wb2) : "v"(p[bb + 2]), "v"(p[bb + 3]));
                asm("v_cvt_pk_bf16_f32 %0, %1, %2" : "=v"(wc)  : "v"(p[bb + 4]), "v"(p[bb + 5]));
                asm("v_cvt_pk_bf16_f32 %0, %1, %2" : "=v"(wd)  : "v"(p[bb + 6]), "v"(p[bb + 7]));
                asm volatile("v_permlane32_swap_b32 %0, %1" : "+v"(wa),  "+v"(wc));
                asm volatile("v_permlane32_swap_b32 %0, %1" : "+v"(wb2), "+v"(wd));
                u32x4 wv; wv[0] = wa; wv[1] = wb2; wv[2] = wc; wv[3] = wd;
                const u16x8 pb = __builtin_bit_cast(u16x8, wv);
                const int kg = (ks << 1) + H;
                u16x8 vf0 = *(const u16x8*)&Vg[l31 * 64        + ((kg ^ dsw0) << 3)];
                u16x8 vf1 = *(const u16x8*)&Vg[(32 + l31) * 64 + ((kg ^ dsw1) << 3)];
                o0 = mfma32(vf0, pb, o0);
                o1 = mfma32(vf1, pb, o1);
                lacc = mfma32(ones1, pb, lacc);
            }
            __builtin_amdgcn_s_setprio(0);
        }

        __syncthreads();   // writes of buf^1 visible; readers of buf done
        cur ^= 1;
    }

    // ---- merge group 0 + group 1 (LSE combine) ----
    // MO: 256 rows x 32 floats = 32 KB = exactly sizeof(Kl).
    const int idx = qw * 64 + lane;
    float* MO = (float*)Kl + idx * 32;
    const float lsum = lacc[0];
    if (grp == 1) {
#pragma unroll
        for (int i = 0; i < 16; ++i) {
            MO[(i + idx) & 31]      = o0[i];
            MO[(16 + i + idx) & 31] = o1[i];
        }
        MLbuf[idx * 2]     = mx;
        MLbuf[idx * 2 + 1] = lsum;
    }
    __syncthreads();
    if (grp == 0) {
        const float m2 = MLbuf[idx * 2], l2 = MLbuf[idx * 2 + 1];
        const float mn = fmaxf(mx, m2);
        const float ea = exp2_hw(mx - mn);
        const float eb = exp2_hw(m2 - mn);
        const float inv = 1.f / (lsum * ea + l2 * eb);
        float* orow = out + ((size_t)(b * S_LEN) + qrow) * EMB + h * DK;
#pragma unroll
        for (int g = 0; g < 4; ++g) {
            f32x4 w0, w1;
#pragma unroll
            for (int i = 0; i < 4; ++i) {
                w0[i] = (o0[4 * g + i] * ea + MO[(4 * g + i + idx) & 31] * eb) * inv;
                w1[i] = (o1[4 * g + i] * ea + MO[(16 + 4 * g + i + idx) & 31] * eb) * inv;
            }
            *(f32x4*)&orow[8 * g + 4 * H]      = w0;
            *(f32x4*)&orow[32 + 8 * g + 4 * H] = w1;
        }
    }
}

// ---------------------------------------------------------------- launch
extern "C" void kernel_launch(void* const* d_in, const int* in_sizes, int n_in,
                              void* d_out, int out_size, void* d_ws, size_t ws_size,
                              hipStream_t stream)
{
    const float* x  = (const float*)d_in[0];
    const float* wq = (const float*)d_in[1];
    const float* bq = (const float*)d_in[2];
    const float* wk = (const float*)d_in[3];
    const float* bk = (const float*)d_in[4];
    const float* wv = (const float*)d_in[5];
    const float* bv = (const float*)d_in[6];
    const int* msk  = (const int*)d_in[7];
    float* out = (float*)d_out;

    unsigned short* xb  = (unsigned short*)d_ws;
    unsigned short* wb  = xb + (size_t)M_TOT * EMB;   // fused [3072][1024]
    unsigned short* qkv = wb + (size_t)3 * 1024 * 1024;

    cvt_kernel<<<7168, 256, 0, stream>>>(x, wq, wk, wv,
                                         xb, wb, wb + 1024 * 1024, wb + 2 * 1024 * 1024);
    qkv_gemm<<<dim3(12, 16, 1), 512, 0, stream>>>(xb, wb, bq, bk, bv, qkv);
    attn_kernel<<<dim3(32, 16, 1), 512, 0, stream>>>(
        qkv, qkv + (size_t)M_TOT * EMB, qkv + (size_t)2 * M_TOT * EMB, msk, out);
}

// Round 14
// 86.650 us; speedup vs baseline: 1.2852x; 1.0153x over previous
//
#include <hip/hip_runtime.h>

#define B_SZ   2
#define NH     16
#define S_LEN  2048
#define DK     64
#define EMB    1024
#define M_TOT  (B_SZ * S_LEN)   // 4096
#define KT     64

typedef float          f32x4  __attribute__((ext_vector_type(4)));
typedef float          f32x16 __attribute__((ext_vector_type(16)));
typedef unsigned int   u32x4  __attribute__((ext_vector_type(4)));
typedef unsigned short u16x8  __attribute__((ext_vector_type(8)));
typedef unsigned short u16x4  __attribute__((ext_vector_type(4)));
typedef __bf16         bf16x8 __attribute__((ext_vector_type(8)));

static __device__ __forceinline__ f32x4 mfma16(u16x8 a, u16x8 b, f32x4 c) {
    return __builtin_amdgcn_mfma_f32_16x16x32_bf16(
        __builtin_bit_cast(bf16x8, a), __builtin_bit_cast(bf16x8, b), c, 0, 0, 0);
}
static __device__ __forceinline__ f32x16 mfma32(u16x8 a, u16x8 b, f32x16 c) {
    return __builtin_amdgcn_mfma_f32_32x32x16_bf16(
        __builtin_bit_cast(bf16x8, a), __builtin_bit_cast(bf16x8, b), c, 0, 0, 0);
}

// round-to-nearest-even fp32 -> bf16 (finite inputs)
static __device__ __forceinline__ unsigned short f2bf(float f) {
    unsigned int u = __builtin_bit_cast(unsigned int, f);
    u = (u + 0x7FFFu + ((u >> 16) & 1u)) >> 16;
    return (unsigned short)u;
}

// hardware 2^x
static __device__ __forceinline__ float exp2_hw(float x) {
    float r; asm("v_exp_f32 %0, %1" : "=v"(r) : "v"(x)); return r;
}

// raw barrier with compiler memory fence (no implicit vmcnt drain)
static __device__ __forceinline__ void barrier_raw() {
    asm volatile("s_barrier" ::: "memory");
}
#define VMCNT8() asm volatile("s_waitcnt vmcnt(8)" ::: "memory")
#define VMCNT4() asm volatile("s_waitcnt vmcnt(4)" ::: "memory")
#define VMCNT0() asm volatile("s_waitcnt vmcnt(0)" ::: "memory")

// async global -> LDS, 16B per lane; LDS dest = uniform base + lane*16
#define GLDS16(g, l)  __builtin_amdgcn_global_load_lds(                      \
    (const void __attribute__((address_space(1)))*)(g),                      \
    (void __attribute__((address_space(3)))*)(l), 16, 0, 0)

// ---------------------------------------------------------------- convert
__global__ __launch_bounds__(256) void cvt_kernel(
    const float* __restrict__ x,  const float* __restrict__ wq,
    const float* __restrict__ wk, const float* __restrict__ wv,
    unsigned short* __restrict__ xb,  unsigned short* __restrict__ wqb,
    unsigned short* __restrict__ wkb, unsigned short* __restrict__ wvb)
{
    long gid = (long)blockIdx.x * 256 + threadIdx.x;
    long e = gid * 4;
    const float* src; unsigned short* dst; long off;
    if      (e < 4194304L) { src = x;  dst = xb;  off = e; }
    else if (e < 5242880L) { src = wq; dst = wqb; off = e - 4194304L; }
    else if (e < 6291456L) { src = wk; dst = wkb; off = e - 5242880L; }
    else                   { src = wv; dst = wvb; off = e - 6291456L; }
    f32x4 v = *(const f32x4*)(src + off);
    u16x4 u;
    u[0] = f2bf(v[0]); u[1] = f2bf(v[1]); u[2] = f2bf(v[2]); u[3] = f2bf(v[3]);
    *(u16x4*)(dst + off) = u;
}

// ---------------------------------------------------------------- QKV GEMM
// Fused single GEMM: C[4096][3072] = xb[4096][1024] * Wfused[3072][1024]^T.
// 256x256 tile, BK=32, 4-deep LDS ring with counted vmcnt(8) (T3+T4).
// XCD-aware bijective block swizzle (T1).
__global__ __launch_bounds__(512) void qkv_gemm(
    const unsigned short* __restrict__ xb,
    const unsigned short* __restrict__ wb,   // fused [3072][1024] bf16
    const float* __restrict__ bq, const float* __restrict__ bk,
    const float* __restrict__ bv,
    unsigned short* __restrict__ qkv)
{
    const int tid  = threadIdx.x;
    const int lane = tid & 63;
    const int wid  = tid >> 6;
    const int wm   = wid >> 2, wn = wid & 3;    // 2 M-waves x 4 N-waves
    const int lid  = blockIdx.y * 12 + blockIdx.x;
    const int nid  = (lid & 7) * 24 + (lid >> 3);
    const int n0   = (nid >> 4) * 256;
    const int m0   = (nid & 15) * 256;
    const int l15  = lane & 15;
    const int k4   = lane >> 4;

    __shared__ __align__(16) unsigned short Al[4][256 * 32];  // 64 KB
    __shared__ __align__(16) unsigned short Bl[4][256 * 32];  // 64 KB

    f32x4 acc[8][4];
#pragma unroll
    for (int i = 0; i < 8; ++i)
#pragma unroll
        for (int j = 0; j < 4; ++j)
            acc[i][j] = (f32x4){0.f, 0.f, 0.f, 0.f};

    const int row0 = tid >> 2, row1 = (512 + tid) >> 2;
    const int sl   = tid & 3;
    const int c0   = (sl ^ (row0 & 3)) << 3;
    const int c1   = (sl ^ (row1 & 3)) << 3;
    const int d0   = (wid * 64) * 8;
    const int d1   = (512 + wid * 64) * 8;
    const unsigned short* gA0 = xb + (size_t)(m0 + row0) * EMB + c0;
    const unsigned short* gA1 = xb + (size_t)(m0 + row1) * EMB + c1;
    const unsigned short* gB0 = wb + (size_t)(n0 + row0) * EMB + c0;
    const unsigned short* gB1 = wb + (size_t)(n0 + row1) * EMB + c1;

#define STAGE_A(kt, b) do {                                     \
        GLDS16(gA0 + (kt) * 32, &Al[b][d0]);                    \
        GLDS16(gA1 + (kt) * 32, &Al[b][d1]); } while (0)
#define STAGE_B(kt, b) do {                                     \
        GLDS16(gB0 + (kt) * 32, &Bl[b][d0]);                    \
        GLDS16(gB1 + (kt) * 32, &Bl[b][d1]); } while (0)

    const int rsl = (k4 ^ (l15 & 3)) << 3;
    const int abase = wm * 128 + l15;
    const int bbase = wn * 64 + l15;

    STAGE_A(0, 0); STAGE_B(0, 0);
    STAGE_A(1, 1); STAGE_B(1, 1);
    STAGE_A(2, 2); STAGE_B(2, 2);
    VMCNT8();
    barrier_raw();

    for (int kt = 0; kt < 32; ++kt) {
        const int b = kt & 3;
        const unsigned short* Ab = Al[b];
        const unsigned short* Bb = Bl[b];

        u16x8 bfr[4], afr[4];
#pragma unroll
        for (int j = 0; j < 4; ++j)
            bfr[j] = *(const u16x8*)&Bb[(bbase + j * 16) * 32 + rsl];
#pragma unroll
        for (int i = 0; i < 4; ++i)
            afr[i] = *(const u16x8*)&Ab[(abase + i * 16) * 32 + rsl];
        if (kt + 3 < 32) STAGE_A(kt + 3, (kt + 3) & 3);
        __builtin_amdgcn_s_setprio(1);
#pragma unroll
        for (int i = 0; i < 4; ++i)
#pragma unroll
            for (int j = 0; j < 4; ++j)
                acc[i][j] = mfma16(afr[i], bfr[j], acc[i][j]);
        __builtin_amdgcn_s_setprio(0);
        barrier_raw();

#pragma unroll
        for (int i = 0; i < 4; ++i)
            afr[i] = *(const u16x8*)&Ab[(abase + (4 + i) * 16) * 32 + rsl];
        if (kt + 3 < 32) STAGE_B(kt + 3, (kt + 3) & 3);
        __builtin_amdgcn_s_setprio(1);
#pragma unroll
        for (int i = 0; i < 4; ++i)
#pragma unroll
            for (int j = 0; j < 4; ++j)
                acc[4 + i][j] = mfma16(afr[i], bfr[j], acc[4 + i][j]);
        __builtin_amdgcn_s_setprio(0);

        if (kt == 29)      VMCNT4();
        else if (kt == 30) VMCNT0();
        else               VMCNT8();
        barrier_raw();
    }

    const int mat = n0 >> 10;
    const float* bias = (mat == 0) ? bq : ((mat == 1) ? bk : bv);
    unsigned short* dst = qkv + (size_t)mat * ((size_t)M_TOT * EMB);
    const int nb = (n0 & 1023) + wn * 64;
#pragma unroll
    for (int fc = 0; fc < 4; ++fc) {
        const int nl = nb + fc * 16 + l15;
        const float bvv = bias[nl];
        const int h = nl >> 6, d = nl & 63;
#pragma unroll
        for (int fr = 0; fr < 8; ++fr) {
#pragma unroll
            for (int rr = 0; rr < 4; ++rr) {
                const int m = m0 + wm * 128 + fr * 16 + k4 * 4 + rr;
                const int bb = m >> 11, s = m & 2047;
                dst[((size_t)((bb * NH + h) * S_LEN + s)) * DK + d] =
                    f2bf(acc[fr][fc][rr] + bvv);
            }
        }
    }
#undef STAGE_A
#undef STAGE_B
}

// ---------------------------------------------------------------- attention
// Round-8 proven inner loop (8 waves = 4 q-waves x 2 K-parity groups,
// double-buffered, swapped QK^T, exp2 softmax, defer-max, lsum ones-MFMA,
// cvt_pk+permlane32), wrapped in SERIAL Q-TILE PAIRING: each block processes
// q-tile yp then 15-yp -> every block has IDENTICAL work (17 iterations
// masked).  Grid 32x8 = 256 blocks = 1/CU: sustained 8 waves/CU, zero
// inter-CU drain imbalance, independent of dispatch mapping.
__global__ __launch_bounds__(512) void attn_kernel(
    const unsigned short* __restrict__ Q,
    const unsigned short* __restrict__ K,
    const unsigned short* __restrict__ V,
    const int* __restrict__ mskp,
    float* __restrict__ out)
{
    const int tid = threadIdx.x, lane = tid & 63, wid = tid >> 6;
    const int grp = wid >> 2, qw = wid & 3;
    const int l31 = lane & 31, H = lane >> 5;
    const int bh = blockIdx.x;
    const int h  = bh & 15, b = bh >> 4;
    const int yp = blockIdx.y;             // 0..7: serial pair (yp, 15-yp)
    const size_t hoff = ((size_t)(b * NH + h)) * S_LEN * DK;
    const unsigned short* Qh = Q + hoff;
    const unsigned short* Kh = K + hoff;
    const unsigned short* Vh = V + hoff;
    const int msk = *mskp;

    __shared__ __align__(16) unsigned short Kl[2][2][64 * 64];  // [grp][buf]
    __shared__ __align__(16) unsigned short Vt[2][2][64 * 64];
    __shared__ float MLbuf[512];

    u16x8 ones1;
#pragma unroll
    for (int i = 0; i < 8; ++i) ones1[i] = 0x3F80;   // bf16 1.0

    const int gt  = tid & 255;              // thread within group
    const int sr0 = gt >> 3, sc8 = gt & 7, sr1 = sr0 + 32;
    const int kwo0 = sr0 * 64 + ((sc8 ^ (sr0 & 7)) << 3);
    const int kwo1 = sr1 * 64 + ((sc8 ^ (sr1 & 7)) << 3);
    const int vwo0 = (((sr0 >> 3) ^ sc8) << 3) + (sr0 & 7);
    const int vwo1 = (((sr1 >> 3) ^ sc8) << 3) + (sr1 & 7);

    const int dsw0 = l31 >> 3, dsw1 = 4 + (l31 >> 3);
    const int rsw  = l31 & 7;
    const float SC2 = 0.125f * 1.4426950408889634f;   // fold log2(e)
    const int idx  = qw * 64 + lane;                  // merge row index

    for (int seg = 0; seg < 2; ++seg) {
        const int qt = seg ? (15 - yp) : yp;
        const int q0 = qt * 128;
        const int ntiles = msk ? (2 * qt + 2) : (S_LEN / KT);  // even
        const int niter  = ntiles >> 1;
        const int qrow = q0 + qw * 32 + l31;
        const int qmin = q0 + qw * 32;

        u16x8 qf[4];
#pragma unroll
        for (int ks = 0; ks < 4; ++ks)
            qf[ks] = *(const u16x8*)(Qh + (size_t)qrow * DK + ks * 16 + H * 8);

        f32x16 o0, o1, lacc;
#pragma unroll
        for (int i = 0; i < 16; ++i) { o0[i] = 0.f; o1[i] = 0.f; lacc[i] = 0.f; }
        float mx = -1e30f;

        // ---- prologue: load tile 'grp' to regs; (seg=1) wait for merge
        //      reads to finish before overwriting Kl/Vt; stage buf0 ----
        u16x8 kr[2], vr[2];
        {
            const unsigned short* K0 = Kh + (size_t)grp * KT * DK;
            const unsigned short* V0 = Vh + (size_t)grp * KT * DK;
            kr[0] = *(const u16x8*)(K0 + (size_t)sr0 * DK + sc8 * 8);
            vr[0] = *(const u16x8*)(V0 + (size_t)sr0 * DK + sc8 * 8);
            kr[1] = *(const u16x8*)(K0 + (size_t)sr1 * DK + sc8 * 8);
            vr[1] = *(const u16x8*)(V0 + (size_t)sr1 * DK + sc8 * 8);
        }
        __syncthreads();
        {
            unsigned short* Kg = Kl[grp][0];
            unsigned short* Vg = Vt[grp][0];
            *(u16x8*)&Kg[kwo0] = kr[0];
            *(u16x8*)&Kg[kwo1] = kr[1];
#pragma unroll
            for (int e = 0; e < 8; ++e) {
                Vg[(sc8 * 8 + e) * 64 + vwo0] = vr[0][e];
                Vg[(sc8 * 8 + e) * 64 + vwo1] = vr[1][e];
            }
            if (grp + 2 < ntiles) {
                const unsigned short* Kn = Kh + (size_t)(grp + 2) * KT * DK;
                const unsigned short* Vn = Vh + (size_t)(grp + 2) * KT * DK;
                kr[0] = *(const u16x8*)(Kn + (size_t)sr0 * DK + sc8 * 8);
                vr[0] = *(const u16x8*)(Vn + (size_t)sr0 * DK + sc8 * 8);
                kr[1] = *(const u16x8*)(Kn + (size_t)sr1 * DK + sc8 * 8);
                vr[1] = *(const u16x8*)(Vn + (size_t)sr1 * DK + sc8 * 8);
            }
        }
        __syncthreads();

        int cur = 0;
        for (int it = 0; it < niter; ++it) {
            const int kt = 2 * it + grp;

            // ---- write NEXT tile (kt+2) into buf^1; overlaps compute ----
            if (kt + 2 < ntiles) {
                unsigned short* Kg = Kl[grp][cur ^ 1];
                unsigned short* Vg = Vt[grp][cur ^ 1];
                *(u16x8*)&Kg[kwo0] = kr[0];
                *(u16x8*)&Kg[kwo1] = kr[1];
#pragma unroll
                for (int e = 0; e < 8; ++e) {
                    Vg[(sc8 * 8 + e) * 64 + vwo0] = vr[0][e];
                    Vg[(sc8 * 8 + e) * 64 + vwo1] = vr[1][e];
                }
            }
            // ---- prefetch tile kt+4 into regs ----
            if (kt + 4 < ntiles) {
                const unsigned short* Kn = Kh + (size_t)(kt + 4) * KT * DK;
                const unsigned short* Vn = Vh + (size_t)(kt + 4) * KT * DK;
                kr[0] = *(const u16x8*)(Kn + (size_t)sr0 * DK + sc8 * 8);
                vr[0] = *(const u16x8*)(Vn + (size_t)sr0 * DK + sc8 * 8);
                kr[1] = *(const u16x8*)(Kn + (size_t)sr1 * DK + sc8 * 8);
                vr[1] = *(const u16x8*)(Vn + (size_t)sr1 * DK + sc8 * 8);
            }

            // ---- compute tile kt from buf[cur] (skip if fully masked) ----
            if (!(msk && kt * KT > qmin + 31)) {
                const unsigned short* Kg = Kl[grp][cur];
                const unsigned short* Vg = Vt[grp][cur];

                // S^T = K Q^T
                f32x16 st0, st1;
#pragma unroll
                for (int i = 0; i < 16; ++i) { st0[i] = 0.f; st1[i] = 0.f; }
                __builtin_amdgcn_s_setprio(1);
#pragma unroll
                for (int ks = 0; ks < 4; ++ks) {
                    const int g = (((ks << 1) + H) ^ rsw) << 3;
                    u16x8 kf0 = *(const u16x8*)&Kg[l31 * 64 + g];
                    u16x8 kf1 = *(const u16x8*)&Kg[(32 + l31) * 64 + g];
                    st0 = mfma32(kf0, qf[ks], st0);
                    st1 = mfma32(kf1, qf[ks], st1);
                }
                __builtin_amdgcn_s_setprio(0);

                // scale (exp2 domain, packed) + causal mask
                st0 *= SC2;
                st1 *= SC2;
                float p[32];
#pragma unroll
                for (int r = 0; r < 16; ++r) { p[r] = st0[r]; p[16 + r] = st1[r]; }
                const bool needmask = msk && (kt * KT + 63 > qrow);
                if (needmask) {
#pragma unroll
                    for (int r = 0; r < 16; ++r) {
                        const int krow = (r & 3) + 8 * (r >> 2) + 4 * H;
                        if (kt * KT + krow > qrow)      p[r]      = -1e30f;
                        if (kt * KT + 32 + krow > qrow) p[16 + r] = -1e30f;
                    }
                }

                // tile max: register tree + one shfl(32); defer-max rescale
                float t8[8];
#pragma unroll
                for (int i = 0; i < 8; ++i)
                    t8[i] = fmaxf(fmaxf(p[i], p[i + 8]), fmaxf(p[i + 16], p[i + 24]));
#pragma unroll
                for (int i = 0; i < 4; ++i) t8[i] = fmaxf(t8[i], t8[i + 4]);
                float mt = fmaxf(fmaxf(t8[0], t8[1]), fmaxf(t8[2], t8[3]));
                mt = fmaxf(mt, __shfl_xor(mt, 32, 64));

                if (!__all(mt <= mx + 11.54f)) {   // 8 nats in log2 domain
                    const float mn = fmaxf(mx, mt);
                    const float al = exp2_hw(mx - mn);
                    mx = mn;
                    o0 *= al; o1 *= al;
                    lacc[0] *= al;
                }

#pragma unroll
                for (int r = 0; r < 32; ++r) p[r] = exp2_hw(p[r] - mx);

                // P^T -> bf16 B-fragments; PV + row-sum via ones-MFMA
                __builtin_amdgcn_s_setprio(1);
#pragma unroll
                for (int ks = 0; ks < 4; ++ks) {
                    const int bb = ks * 8;
                    unsigned int wa, wb2, wc, wd;
                    asm("v_cvt_pk_bf16_f32 %0, %1, %2" : "=v"(wa)  : "v"(p[bb + 0]), "v"(p[bb + 1]));
                    asm("v_cvt_pk_bf16_f32 %0, %1, %2" : "=v"(wb2) : "v"(p[bb + 2]), "v"(p[bb + 3]));
                    asm("v_cvt_pk_bf16_f32 %0, %1, %2" : "=v"(wc)  : "v"(p[bb + 4]), "v"(p[bb + 5]));
                    asm("v_cvt_pk_bf16_f32 %0, %1, %2" : "=v"(wd)  : "v"(p[bb + 6]), "v"(p[bb + 7]));
                    asm volatile("v_permlane32_swap_b32 %0, %1" : "+v"(wa),  "+v"(wc));
                    asm volatile("v_permlane32_swap_b32 %0, %1" : "+v"(wb2), "+v"(wd));
                    u32x4 wv; wv[0] = wa; wv[1] = wb2; wv[2] = wc; wv[3] = wd;
                    const u16x8 pb = __builtin_bit_cast(u16x8, wv);
                    const int kg = (ks << 1) + H;
                    u16x8 vf0 = *(const u16x8*)&Vg[l31 * 64        + ((kg ^ dsw0) << 3)];
                    u16x8 vf1 = *(const u16x8*)&Vg[(32 + l31) * 64 + ((kg ^ dsw1) << 3)];
                    o0 = mfma32(vf0, pb, o0);
                    o1 = mfma32(vf1, pb, o1);
                    lacc = mfma32(ones1, pb, lacc);
                }
                __builtin_amdgcn_s_setprio(0);
            }

            __syncthreads();   // buf^1 writes visible; buf readers done
            cur ^= 1;
        }

        // ---- merge group 0 + group 1 (LSE combine) ----
        // MO: 256 rows x 32 floats = 32 KB = exactly sizeof(Kl).
        float* MO = (float*)Kl + idx * 32;
        const float lsum = lacc[0];
        if (grp == 1) {
#pragma unroll
            for (int i = 0; i < 16; ++i) {
                MO[(i + idx) & 31]      = o0[i];
                MO[(16 + i + idx) & 31] = o1[i];
            }
            MLbuf[idx * 2]     = mx;
            MLbuf[idx * 2 + 1] = lsum;
        }
        __syncthreads();
        if (grp == 0) {
            const float m2 = MLbuf[idx * 2], l2 = MLbuf[idx * 2 + 1];
            const float mn = fmaxf(mx, m2);
            const float ea = exp2_hw(mx - mn);
            const float eb = exp2_hw(m2 - mn);
            const float inv = 1.f / (lsum * ea + l2 * eb);
            float* orow = out + ((size_t)(b * S_LEN) + qrow) * EMB + h * DK;
#pragma unroll
            for (int g = 0; g < 4; ++g) {
                f32x4 w0, w1;
#pragma unroll
                for (int i = 0; i < 4; ++i) {
                    w0[i] = (o0[4 * g + i] * ea + MO[(4 * g + i + idx) & 31] * eb) * inv;
                    w1[i] = (o1[4 * g + i] * ea + MO[(16 + 4 * g + i + idx) & 31] * eb) * inv;
                }
                *(f32x4*)&orow[8 * g + 4 * H]      = w0;
                *(f32x4*)&orow[32 + 8 * g + 4 * H] = w1;
            }
        }
        // next seg's prologue __syncthreads guards MO reads vs restaging
    }
}

// ---------------------------------------------------------------- launch
extern "C" void kernel_launch(void* const* d_in, const int* in_sizes, int n_in,
                              void* d_out, int out_size, void* d_ws, size_t ws_size,
                              hipStream_t stream)
{
    const float* x  = (const float*)d_in[0];
    const float* wq = (const float*)d_in[1];
    const float* bq = (const float*)d_in[2];
    const float* wk = (const float*)d_in[3];
    const float* bk = (const float*)d_in[4];
    const float* wv = (const float*)d_in[5];
    const float* bv = (const float*)d_in[6];
    const int* msk  = (const int*)d_in[7];
    float* out = (float*)d_out;

    unsigned short* xb  = (unsigned short*)d_ws;
    unsigned short* wb  = xb + (size_t)M_TOT * EMB;   // fused [3072][1024]
    unsigned short* qkv = wb + (size_t)3 * 1024 * 1024;

    cvt_kernel<<<7168, 256, 0, stream>>>(x, wq, wk, wv,
                                         xb, wb, wb + 1024 * 1024, wb + 2 * 1024 * 1024);
    qkv_gemm<<<dim3(12, 16, 1), 512, 0, stream>>>(xb, wb, bq, bk, bv, qkv);
    attn_kernel<<<dim3(32, 8, 1), 512, 0, stream>>>(
        qkv, qkv + (size_t)M_TOT * EMB, qkv + (size_t)2 * M_TOT * EMB, msk, out);
}

// Round 15
// 86.007 us; speedup vs baseline: 1.2948x; 1.0075x over previous
//
#include <hip/hip_runtime.h>

#define B_SZ   2
#define NH     16
#define S_LEN  2048
#define DK     64
#define EMB    1024
#define M_TOT  (B_SZ * S_LEN)   // 4096
#define KT     64

typedef float          f32x4  __attribute__((ext_vector_type(4)));
typedef float          f32x16 __attribute__((ext_vector_type(16)));
typedef unsigned int   u32x4  __attribute__((ext_vector_type(4)));
typedef unsigned short u16x8  __attribute__((ext_vector_type(8)));
typedef unsigned short u16x4  __attribute__((ext_vector_type(4)));
typedef __bf16         bf16x8 __attribute__((ext_vector_type(8)));

static __device__ __forceinline__ f32x4 mfma16(u16x8 a, u16x8 b, f32x4 c) {
    return __builtin_amdgcn_mfma_f32_16x16x32_bf16(
        __builtin_bit_cast(bf16x8, a), __builtin_bit_cast(bf16x8, b), c, 0, 0, 0);
}
static __device__ __forceinline__ f32x16 mfma32(u16x8 a, u16x8 b, f32x16 c) {
    return __builtin_amdgcn_mfma_f32_32x32x16_bf16(
        __builtin_bit_cast(bf16x8, a), __builtin_bit_cast(bf16x8, b), c, 0, 0, 0);
}

// round-to-nearest-even fp32 -> bf16 (finite inputs)
static __device__ __forceinline__ unsigned short f2bf(float f) {
    unsigned int u = __builtin_bit_cast(unsigned int, f);
    u = (u + 0x7FFFu + ((u >> 16) & 1u)) >> 16;
    return (unsigned short)u;
}

// hardware 2^x
static __device__ __forceinline__ float exp2_hw(float x) {
    float r; asm("v_exp_f32 %0, %1" : "=v"(r) : "v"(x)); return r;
}

// raw barrier with compiler memory fence (no implicit vmcnt drain)
static __device__ __forceinline__ void barrier_raw() {
    asm volatile("s_barrier" ::: "memory");
}
#define VMCNT8() asm volatile("s_waitcnt vmcnt(8)" ::: "memory")
#define VMCNT4() asm volatile("s_waitcnt vmcnt(4)" ::: "memory")
#define VMCNT0() asm volatile("s_waitcnt vmcnt(0)" ::: "memory")

// async global -> LDS, 16B per lane; LDS dest = uniform base + lane*16
#define GLDS16(g, l)  __builtin_amdgcn_global_load_lds(                      \
    (const void __attribute__((address_space(1)))*)(g),                      \
    (void __attribute__((address_space(3)))*)(l), 16, 0, 0)

// ---------------------------------------------------------------- convert
__global__ __launch_bounds__(256) void cvt_kernel(
    const float* __restrict__ x,  const float* __restrict__ wq,
    const float* __restrict__ wk, const float* __restrict__ wv,
    unsigned short* __restrict__ xb,  unsigned short* __restrict__ wqb,
    unsigned short* __restrict__ wkb, unsigned short* __restrict__ wvb)
{
    long gid = (long)blockIdx.x * 256 + threadIdx.x;
    long e = gid * 4;
    const float* src; unsigned short* dst; long off;
    if      (e < 4194304L) { src = x;  dst = xb;  off = e; }
    else if (e < 5242880L) { src = wq; dst = wqb; off = e - 4194304L; }
    else if (e < 6291456L) { src = wk; dst = wkb; off = e - 5242880L; }
    else                   { src = wv; dst = wvb; off = e - 6291456L; }
    f32x4 v = *(const f32x4*)(src + off);
    u16x4 u;
    u[0] = f2bf(v[0]); u[1] = f2bf(v[1]); u[2] = f2bf(v[2]); u[3] = f2bf(v[3]);
    *(u16x4*)(dst + off) = u;
}

// ---------------------------------------------------------------- QKV GEMM
// Fused single GEMM: C[4096][3072] = xb[4096][1024] * Wfused[3072][1024]^T.
// 256x256 tile, BK=32, 4-deep LDS ring with counted vmcnt(8) (T3+T4).
// XCD-aware bijective block swizzle (T1).  setprio kept: this is the
// phase-split counted-vmcnt regime where it pays (m218b).
__global__ __launch_bounds__(512) void qkv_gemm(
    const unsigned short* __restrict__ xb,
    const unsigned short* __restrict__ wb,   // fused [3072][1024] bf16
    const float* __restrict__ bq, const float* __restrict__ bk,
    const float* __restrict__ bv,
    unsigned short* __restrict__ qkv)
{
    const int tid  = threadIdx.x;
    const int lane = tid & 63;
    const int wid  = tid >> 6;
    const int wm   = wid >> 2, wn = wid & 3;    // 2 M-waves x 4 N-waves
    const int lid  = blockIdx.y * 12 + blockIdx.x;
    const int nid  = (lid & 7) * 24 + (lid >> 3);
    const int n0   = (nid >> 4) * 256;
    const int m0   = (nid & 15) * 256;
    const int l15  = lane & 15;
    const int k4   = lane >> 4;

    __shared__ __align__(16) unsigned short Al[4][256 * 32];  // 64 KB
    __shared__ __align__(16) unsigned short Bl[4][256 * 32];  // 64 KB

    f32x4 acc[8][4];
#pragma unroll
    for (int i = 0; i < 8; ++i)
#pragma unroll
        for (int j = 0; j < 4; ++j)
            acc[i][j] = (f32x4){0.f, 0.f, 0.f, 0.f};

    const int row0 = tid >> 2, row1 = (512 + tid) >> 2;
    const int sl   = tid & 3;
    const int c0   = (sl ^ (row0 & 3)) << 3;
    const int c1   = (sl ^ (row1 & 3)) << 3;
    const int d0   = (wid * 64) * 8;
    const int d1   = (512 + wid * 64) * 8;
    const unsigned short* gA0 = xb + (size_t)(m0 + row0) * EMB + c0;
    const unsigned short* gA1 = xb + (size_t)(m0 + row1) * EMB + c1;
    const unsigned short* gB0 = wb + (size_t)(n0 + row0) * EMB + c0;
    const unsigned short* gB1 = wb + (size_t)(n0 + row1) * EMB + c1;

#define STAGE_A(kt, b) do {                                     \
        GLDS16(gA0 + (kt) * 32, &Al[b][d0]);                    \
        GLDS16(gA1 + (kt) * 32, &Al[b][d1]); } while (0)
#define STAGE_B(kt, b) do {                                     \
        GLDS16(gB0 + (kt) * 32, &Bl[b][d0]);                    \
        GLDS16(gB1 + (kt) * 32, &Bl[b][d1]); } while (0)

    const int rsl = (k4 ^ (l15 & 3)) << 3;
    const int abase = wm * 128 + l15;
    const int bbase = wn * 64 + l15;

    STAGE_A(0, 0); STAGE_B(0, 0);
    STAGE_A(1, 1); STAGE_B(1, 1);
    STAGE_A(2, 2); STAGE_B(2, 2);
    VMCNT8();
    barrier_raw();

    for (int kt = 0; kt < 32; ++kt) {
        const int b = kt & 3;
        const unsigned short* Ab = Al[b];
        const unsigned short* Bb = Bl[b];

        u16x8 bfr[4], afr[4];
#pragma unroll
        for (int j = 0; j < 4; ++j)
            bfr[j] = *(const u16x8*)&Bb[(bbase + j * 16) * 32 + rsl];
#pragma unroll
        for (int i = 0; i < 4; ++i)
            afr[i] = *(const u16x8*)&Ab[(abase + i * 16) * 32 + rsl];
        if (kt + 3 < 32) STAGE_A(kt + 3, (kt + 3) & 3);
        __builtin_amdgcn_s_setprio(1);
#pragma unroll
        for (int i = 0; i < 4; ++i)
#pragma unroll
            for (int j = 0; j < 4; ++j)
                acc[i][j] = mfma16(afr[i], bfr[j], acc[i][j]);
        __builtin_amdgcn_s_setprio(0);
        barrier_raw();

#pragma unroll
        for (int i = 0; i < 4; ++i)
            afr[i] = *(const u16x8*)&Ab[(abase + (4 + i) * 16) * 32 + rsl];
        if (kt + 3 < 32) STAGE_B(kt + 3, (kt + 3) & 3);
        __builtin_amdgcn_s_setprio(1);
#pragma unroll
        for (int i = 0; i < 4; ++i)
#pragma unroll
            for (int j = 0; j < 4; ++j)
                acc[4 + i][j] = mfma16(afr[i], bfr[j], acc[4 + i][j]);
        __builtin_amdgcn_s_setprio(0);

        if (kt == 29)      VMCNT4();
        else if (kt == 30) VMCNT0();
        else               VMCNT8();
        barrier_raw();
    }

    const int mat = n0 >> 10;
    const float* bias = (mat == 0) ? bq : ((mat == 1) ? bk : bv);
    unsigned short* dst = qkv + (size_t)mat * ((size_t)M_TOT * EMB);
    const int nb = (n0 & 1023) + wn * 64;
#pragma unroll
    for (int fc = 0; fc < 4; ++fc) {
        const int nl = nb + fc * 16 + l15;
        const float bvv = bias[nl];
        const int h = nl >> 6, d = nl & 63;
#pragma unroll
        for (int fr = 0; fr < 8; ++fr) {
#pragma unroll
            for (int rr = 0; rr < 4; ++rr) {
                const int m = m0 + wm * 128 + fr * 16 + k4 * 4 + rr;
                const int bb = m >> 11, s = m & 2047;
                dst[((size_t)((bb * NH + h) * S_LEN + s)) * DK + d] =
                    f2bf(acc[fr][fc][rr] + bvv);
            }
        }
    }
#undef STAGE_A
#undef STAGE_B
}

// ---------------------------------------------------------------- attention
// Round-14 structure (serial q-tile pairing, double-buffered, swapped QK^T,
// exp2 softmax, defer-max, lsum ones-MFMA, cvt_pk+permlane32) with ALL
// s_setprio REMOVED: m190 shows setprio hurts barrier-locked lockstep
// structures (it deprioritizes the SIMD-mate wave's issue -> serializes the
// 2 waves/SIMD).  A/B vs round 14: only this change.
__global__ __launch_bounds__(512) void attn_kernel(
    const unsigned short* __restrict__ Q,
    const unsigned short* __restrict__ K,
    const unsigned short* __restrict__ V,
    const int* __restrict__ mskp,
    float* __restrict__ out)
{
    const int tid = threadIdx.x, lane = tid & 63, wid = tid >> 6;
    const int grp = wid >> 2, qw = wid & 3;
    const int l31 = lane & 31, H = lane >> 5;
    const int bh = blockIdx.x;
    const int h  = bh & 15, b = bh >> 4;
    const int yp = blockIdx.y;             // 0..7: serial pair (yp, 15-yp)
    const size_t hoff = ((size_t)(b * NH + h)) * S_LEN * DK;
    const unsigned short* Qh = Q + hoff;
    const unsigned short* Kh = K + hoff;
    const unsigned short* Vh = V + hoff;
    const int msk = *mskp;

    __shared__ __align__(16) unsigned short Kl[2][2][64 * 64];  // [grp][buf]
    __shared__ __align__(16) unsigned short Vt[2][2][64 * 64];
    __shared__ float MLbuf[512];

    u16x8 ones1;
#pragma unroll
    for (int i = 0; i < 8; ++i) ones1[i] = 0x3F80;   // bf16 1.0

    const int gt  = tid & 255;              // thread within group
    const int sr0 = gt >> 3, sc8 = gt & 7, sr1 = sr0 + 32;
    const int kwo0 = sr0 * 64 + ((sc8 ^ (sr0 & 7)) << 3);
    const int kwo1 = sr1 * 64 + ((sc8 ^ (sr1 & 7)) << 3);
    const int vwo0 = (((sr0 >> 3) ^ sc8) << 3) + (sr0 & 7);
    const int vwo1 = (((sr1 >> 3) ^ sc8) << 3) + (sr1 & 7);

    const int dsw0 = l31 >> 3, dsw1 = 4 + (l31 >> 3);
    const int rsw  = l31 & 7;
    const float SC2 = 0.125f * 1.4426950408889634f;   // fold log2(e)
    const int idx  = qw * 64 + lane;                  // merge row index

    for (int seg = 0; seg < 2; ++seg) {
        const int qt = seg ? (15 - yp) : yp;
        const int q0 = qt * 128;
        const int ntiles = msk ? (2 * qt + 2) : (S_LEN / KT);  // even
        const int niter  = ntiles >> 1;
        const int qrow = q0 + qw * 32 + l31;
        const int qmin = q0 + qw * 32;

        u16x8 qf[4];
#pragma unroll
        for (int ks = 0; ks < 4; ++ks)
            qf[ks] = *(const u16x8*)(Qh + (size_t)qrow * DK + ks * 16 + H * 8);

        f32x16 o0, o1, lacc;
#pragma unroll
        for (int i = 0; i < 16; ++i) { o0[i] = 0.f; o1[i] = 0.f; lacc[i] = 0.f; }
        float mx = -1e30f;

        // ---- prologue: load tile 'grp' to regs; (seg=1) wait for merge
        //      reads to finish before overwriting Kl/Vt; stage buf0 ----
        u16x8 kr[2], vr[2];
        {
            const unsigned short* K0 = Kh + (size_t)grp * KT * DK;
            const unsigned short* V0 = Vh + (size_t)grp * KT * DK;
            kr[0] = *(const u16x8*)(K0 + (size_t)sr0 * DK + sc8 * 8);
            vr[0] = *(const u16x8*)(V0 + (size_t)sr0 * DK + sc8 * 8);
            kr[1] = *(const u16x8*)(K0 + (size_t)sr1 * DK + sc8 * 8);
            vr[1] = *(const u16x8*)(V0 + (size_t)sr1 * DK + sc8 * 8);
        }
        __syncthreads();
        {
            unsigned short* Kg = Kl[grp][0];
            unsigned short* Vg = Vt[grp][0];
            *(u16x8*)&Kg[kwo0] = kr[0];
            *(u16x8*)&Kg[kwo1] = kr[1];
#pragma unroll
            for (int e = 0; e < 8; ++e) {
                Vg[(sc8 * 8 + e) * 64 + vwo0] = vr[0][e];
                Vg[(sc8 * 8 + e) * 64 + vwo1] = vr[1][e];
            }
            if (grp + 2 < ntiles) {
                const unsigned short* Kn = Kh + (size_t)(grp + 2) * KT * DK;
                const unsigned short* Vn = Vh + (size_t)(grp + 2) * KT * DK;
                kr[0] = *(const u16x8*)(Kn + (size_t)sr0 * DK + sc8 * 8);
                vr[0] = *(const u16x8*)(Vn + (size_t)sr0 * DK + sc8 * 8);
                kr[1] = *(const u16x8*)(Kn + (size_t)sr1 * DK + sc8 * 8);
                vr[1] = *(const u16x8*)(Vn + (size_t)sr1 * DK + sc8 * 8);
            }
        }
        __syncthreads();

        int cur = 0;
        for (int it = 0; it < niter; ++it) {
            const int kt = 2 * it + grp;

            // ---- write NEXT tile (kt+2) into buf^1; overlaps compute ----
            if (kt + 2 < ntiles) {
                unsigned short* Kg = Kl[grp][cur ^ 1];
                unsigned short* Vg = Vt[grp][cur ^ 1];
                *(u16x8*)&Kg[kwo0] = kr[0];
                *(u16x8*)&Kg[kwo1] = kr[1];
#pragma unroll
                for (int e = 0; e < 8; ++e) {
                    Vg[(sc8 * 8 + e) * 64 + vwo0] = vr[0][e];
                    Vg[(sc8 * 8 + e) * 64 + vwo1] = vr[1][e];
                }
            }
            // ---- prefetch tile kt+4 into regs ----
            if (kt + 4 < ntiles) {
                const unsigned short* Kn = Kh + (size_t)(kt + 4) * KT * DK;
                const unsigned short* Vn = Vh + (size_t)(kt + 4) * KT * DK;
                kr[0] = *(const u16x8*)(Kn + (size_t)sr0 * DK + sc8 * 8);
                vr[0] = *(const u16x8*)(Vn + (size_t)sr0 * DK + sc8 * 8);
                kr[1] = *(const u16x8*)(Kn + (size_t)sr1 * DK + sc8 * 8);
                vr[1] = *(const u16x8*)(Vn + (size_t)sr1 * DK + sc8 * 8);
            }

            // ---- compute tile kt from buf[cur] (skip if fully masked) ----
            if (!(msk && kt * KT > qmin + 31)) {
                const unsigned short* Kg = Kl[grp][cur];
                const unsigned short* Vg = Vt[grp][cur];

                // S^T = K Q^T
                f32x16 st0, st1;
#pragma unroll
                for (int i = 0; i < 16; ++i) { st0[i] = 0.f; st1[i] = 0.f; }
#pragma unroll
                for (int ks = 0; ks < 4; ++ks) {
                    const int g = (((ks << 1) + H) ^ rsw) << 3;
                    u16x8 kf0 = *(const u16x8*)&Kg[l31 * 64 + g];
                    u16x8 kf1 = *(const u16x8*)&Kg[(32 + l31) * 64 + g];
                    st0 = mfma32(kf0, qf[ks], st0);
                    st1 = mfma32(kf1, qf[ks], st1);
                }

                // scale (exp2 domain, packed) + causal mask
                st0 *= SC2;
                st1 *= SC2;
                float p[32];
#pragma unroll
                for (int r = 0; r < 16; ++r) { p[r] = st0[r]; p[16 + r] = st1[r]; }
                const bool needmask = msk && (kt * KT + 63 > qrow);
                if (needmask) {
#pragma unroll
                    for (int r = 0; r < 16; ++r) {
                        const int krow = (r & 3) + 8 * (r >> 2) + 4 * H;
                        if (kt * KT + krow > qrow)      p[r]      = -1e30f;
                        if (kt * KT + 32 + krow > qrow) p[16 + r] = -1e30f;
                    }
                }

                // tile max: register tree + one shfl(32); defer-max rescale
                float t8[8];
#pragma unroll
                for (int i = 0; i < 8; ++i)
                    t8[i] = fmaxf(fmaxf(p[i], p[i + 8]), fmaxf(p[i + 16], p[i + 24]));
#pragma unroll
                for (int i = 0; i < 4; ++i) t8[i] = fmaxf(t8[i], t8[i + 4]);
                float mt = fmaxf(fmaxf(t8[0], t8[1]), fmaxf(t8[2], t8[3]));
                mt = fmaxf(mt, __shfl_xor(mt, 32, 64));

                if (!__all(mt <= mx + 11.54f)) {   // 8 nats in log2 domain
                    const float mn = fmaxf(mx, mt);
                    const float al = exp2_hw(mx - mn);
                    mx = mn;
                    o0 *= al; o1 *= al;
                    lacc[0] *= al;
                }

#pragma unroll
                for (int r = 0; r < 32; ++r) p[r] = exp2_hw(p[r] - mx);

                // P^T -> bf16 B-fragments; PV + row-sum via ones-MFMA
#pragma unroll
                for (int ks = 0; ks < 4; ++ks) {
                    const int bb = ks * 8;
                    unsigned int wa, wb2, wc, wd;
                    asm("v_cvt_pk_bf16_f32 %0, %1, %2" : "=v"(wa)  : "v"(p[bb + 0]), "v"(p[bb + 1]));
                    asm("v_cvt_pk_bf16_f32 %0, %1, %2" : "=v"(wb2) : "v"(p[bb + 2]), "v"(p[bb + 3]));
                    asm("v_cvt_pk_bf16_f32 %0, %1, %2" : "=v"(wc)  : "v"(p[bb + 4]), "v"(p[bb + 5]));
                    asm("v_cvt_pk_bf16_f32 %0, %1, %2" : "=v"(wd)  : "v"(p[bb + 6]), "v"(p[bb + 7]));
                    asm volatile("v_permlane32_swap_b32 %0, %1" : "+v"(wa),  "+v"(wc));
                    asm volatile("v_permlane32_swap_b32 %0, %1" : "+v"(wb2), "+v"(wd));
                    u32x4 wv; wv[0] = wa; wv[1] = wb2; wv[2] = wc; wv[3] = wd;
                    const u16x8 pb = __builtin_bit_cast(u16x8, wv);
                    const int kg = (ks << 1) + H;
                    u16x8 vf0 = *(const u16x8*)&Vg[l31 * 64        + ((kg ^ dsw0) << 3)];
                    u16x8 vf1 = *(const u16x8*)&Vg[(32 + l31) * 64 + ((kg ^ dsw1) << 3)];
                    o0 = mfma32(vf0, pb, o0);
                    o1 = mfma32(vf1, pb, o1);
                    lacc = mfma32(ones1, pb, lacc);
                }
            }

            __syncthreads();   // buf^1 writes visible; buf readers done
            cur ^= 1;
        }

        // ---- merge group 0 + group 1 (LSE combine) ----
        // MO: 256 rows x 32 floats = 32 KB = exactly sizeof(Kl).
        float* MO = (float*)Kl + idx * 32;
        const float lsum = lacc[0];
        if (grp == 1) {
#pragma unroll
            for (int i = 0; i < 16; ++i) {
                MO[(i + idx) & 31]      = o0[i];
                MO[(16 + i + idx) & 31] = o1[i];
            }
            MLbuf[idx * 2]     = mx;
            MLbuf[idx * 2 + 1] = lsum;
        }
        __syncthreads();
        if (grp == 0) {
            const float m2 = MLbuf[idx * 2], l2 = MLbuf[idx * 2 + 1];
            const float mn = fmaxf(mx, m2);
            const float ea = exp2_hw(mx - mn);
            const float eb = exp2_hw(m2 - mn);
            const float inv = 1.f / (lsum * ea + l2 * eb);
            float* orow = out + ((size_t)(b * S_LEN) + qrow) * EMB + h * DK;
#pragma unroll
            for (int g = 0; g < 4; ++g) {
                f32x4 w0, w1;
#pragma unroll
                for (int i = 0; i < 4; ++i) {
                    w0[i] = (o0[4 * g + i] * ea + MO[(4 * g + i + idx) & 31] * eb) * inv;
                    w1[i] = (o1[4 * g + i] * ea + MO[(16 + 4 * g + i + idx) & 31] * eb) * inv;
                }
                *(f32x4*)&orow[8 * g + 4 * H]      = w0;
                *(f32x4*)&orow[32 + 8 * g + 4 * H] = w1;
            }
        }
        // next seg's prologue __syncthreads guards MO reads vs restaging
    }
}

// ---------------------------------------------------------------- launch
extern "C" void kernel_launch(void* const* d_in, const int* in_sizes, int n_in,
                              void* d_out, int out_size, void* d_ws, size_t ws_size,
                              hipStream_t stream)
{
    const float* x  = (const float*)d_in[0];
    const float* wq = (const float*)d_in[1];
    const float* bq = (const float*)d_in[2];
    const float* wk = (const float*)d_in[3];
    const float* bk = (const float*)d_in[4];
    const float* wv = (const float*)d_in[5];
    const float* bv = (const float*)d_in[6];
    const int* msk  = (const int*)d_in[7];
    float* out = (float*)d_out;

    unsigned short* xb  = (unsigned short*)d_ws;
    unsigned short* wb  = xb + (size_t)M_TOT * EMB;   // fused [3072][1024]
    unsigned short* qkv = wb + (size_t)3 * 1024 * 1024;

    cvt_kernel<<<7168, 256, 0, stream>>>(x, wq, wk, wv,
                                         xb, wb, wb + 1024 * 1024, wb + 2 * 1024 * 1024);
    qkv_gemm<<<dim3(12, 16, 1), 512, 0, stream>>>(xb, wb, bq, bk, bv, qkv);
    attn_kernel<<<dim3(32, 8, 1), 512, 0, stream>>>(
        qkv, qkv + (size_t)M_TOT * EMB, qkv + (size_t)2 * M_TOT * EMB, msk, out);
}